// Round 1
// baseline (2202.631 us; speedup 1.0000x reference)
//
#include <hip/hip_runtime.h>

// FLASH_6073083756839 — fused gated-attention block, fp32 baseline.
// Pipeline (4 dispatches, one templated tiled GEMM):
//  MODE 0: uvb = silu(X @ W_uv + b_uv) -> scatter u, v, q(=base*g0+b0), k(=base*g1+b1)
//  MODE 1: sq = relu((q @ k^T)/S)^2            (batched over B, B^T access)
//  MODE 2: u  = u * (sq @ v)                   (batched, in-place elementwise)
//  MODE 3: out = u @ W_out + b_out
// All dims are multiples of 128 -> no bounds checks anywhere.

#define H_DIM  1024
#define E_DIM  2048
#define SD     128
#define B_SZ   4
#define S_LEN  2048
#define M_TOT  (B_SZ * S_LEN)          // 8192
#define F_DIM  (2 * E_DIM + SD)        // 4224

template <int MODE>
__global__ __launch_bounds__(256) void gemm_k(
    const float* __restrict__ Ag, const float* __restrict__ Bg,
    float* __restrict__ O0, float* __restrict__ O1,
    float* __restrict__ O2, float* __restrict__ O3,
    const float* __restrict__ E0, const float* __restrict__ E1,
    const float* __restrict__ E2)
{
    constexpr int BM = 128, BN = 128, BK = 16;
    constexpr bool TB  = (MODE == 1);  // B given as N x K (compute A @ B^T)
    constexpr int K    = (MODE == 0) ? H_DIM : (MODE == 1) ? SD : E_DIM;
    constexpr int lda  = (MODE == 0) ? H_DIM : (MODE == 1) ? SD : E_DIM;
    constexpr int ldb  = (MODE == 0) ? F_DIM : (MODE == 1) ? SD
                        : (MODE == 2) ? E_DIM : H_DIM;

    const int z = blockIdx.z;
    const float* A = Ag + ((MODE == 1) ? (long)z * S_LEN * SD
                        : (MODE == 2) ? (long)z * S_LEN * S_LEN : 0L);
    const float* Bp = Bg + ((MODE == 1) ? (long)z * S_LEN * SD
                         : (MODE == 2) ? (long)z * S_LEN * E_DIM : 0L);

    __shared__ float As[BK][BM + 4];   // stored transposed: As[k][m]
    __shared__ float Bs[BK][BN + 4];   // Bs[k][n]

    const int t  = threadIdx.x;
    const int m0 = blockIdx.y * BM;
    const int n0 = blockIdx.x * BN;

    // A-tile (and transposed-B-tile) load mapping: 128 rows x 16 k, 8 elems/thread
    const int arow = t >> 1;           // 0..127
    const int acol = (t & 1) * 8;      // 0 or 8
    // normal B-tile load mapping: 16 k x 128 n
    const int brow = t >> 4;           // 0..15
    const int bcol = (t & 15) * 8;     // 0..120

    // micro-tile position
    const int tm = (t >> 4) * 8;       // 0..120
    const int tn = (t & 15) * 8;       // 0..120

    float acc[8][8];
#pragma unroll
    for (int i = 0; i < 8; i++)
#pragma unroll
        for (int j = 0; j < 8; j++) acc[i][j] = 0.f;

    for (int k0 = 0; k0 < K; k0 += BK) {
        {   // A tile -> As[k][m]
            const float* src = A + (long)(m0 + arow) * lda + k0 + acol;
            float4 a0 = *(const float4*)(src);
            float4 a1 = *(const float4*)(src + 4);
            As[acol + 0][arow] = a0.x; As[acol + 1][arow] = a0.y;
            As[acol + 2][arow] = a0.z; As[acol + 3][arow] = a0.w;
            As[acol + 4][arow] = a1.x; As[acol + 5][arow] = a1.y;
            As[acol + 6][arow] = a1.z; As[acol + 7][arow] = a1.w;
        }
        if (TB) {   // B is N x K: Bs[k][n] = B[n][k]
            const float* src = Bp + (long)(n0 + arow) * ldb + k0 + acol;
            float4 b0 = *(const float4*)(src);
            float4 b1 = *(const float4*)(src + 4);
            Bs[acol + 0][arow] = b0.x; Bs[acol + 1][arow] = b0.y;
            Bs[acol + 2][arow] = b0.z; Bs[acol + 3][arow] = b0.w;
            Bs[acol + 4][arow] = b1.x; Bs[acol + 5][arow] = b1.y;
            Bs[acol + 6][arow] = b1.z; Bs[acol + 7][arow] = b1.w;
        } else {    // B is K x N
            const float* src = Bp + (long)(k0 + brow) * ldb + n0 + bcol;
            float4 b0 = *(const float4*)(src);
            float4 b1 = *(const float4*)(src + 4);
            *(float4*)&Bs[brow][bcol]     = b0;
            *(float4*)&Bs[brow][bcol + 4] = b1;
        }
        __syncthreads();

#pragma unroll
        for (int kk = 0; kk < BK; kk++) {
            float a[8], b[8];
            *(float4*)&a[0] = *(const float4*)&As[kk][tm];
            *(float4*)&a[4] = *(const float4*)&As[kk][tm + 4];
            *(float4*)&b[0] = *(const float4*)&Bs[kk][tn];
            *(float4*)&b[4] = *(const float4*)&Bs[kk][tn + 4];
#pragma unroll
            for (int i = 0; i < 8; i++)
#pragma unroll
                for (int j = 0; j < 8; j++) acc[i][j] += a[i] * b[j];
        }
        __syncthreads();
    }

    // ---------------- epilogues ----------------
#pragma unroll
    for (int i = 0; i < 8; i++) {
        const int r = m0 + tm + i;
#pragma unroll
        for (int j = 0; j < 8; j++) {
            const int c = n0 + tn + j;
            float x = acc[i][j];
            if (MODE == 0) {
                x += E0[c];                        // + b_uv
                float s = x / (1.f + __expf(-x));  // silu
                if (c < E_DIM) {
                    O0[(long)r * E_DIM + c] = s;                   // u
                } else if (c < 2 * E_DIM) {
                    O1[(long)r * E_DIM + (c - E_DIM)] = s;         // v
                } else {
                    int jj = c - 2 * E_DIM;
                    O2[(long)r * SD + jj] = s * E1[jj]       + E2[jj];        // q
                    O3[(long)r * SD + jj] = s * E1[SD + jj]  + E2[SD + jj];   // k
                }
            } else if (MODE == 1) {
                x *= (1.0f / (float)S_LEN);
                x = fmaxf(x, 0.f);
                O0[(long)z * S_LEN * S_LEN + (long)r * S_LEN + c] = x * x;    // sq
            } else if (MODE == 2) {
                long idx = (long)z * S_LEN * E_DIM + (long)r * E_DIM + c;
                O0[idx] = O0[idx] * x;             // u *= attn_v (in place)
            } else { // MODE 3
                O0[(long)r * H_DIM + c] = x + E0[c];  // + b_out
            }
        }
    }
}

extern "C" void kernel_launch(void* const* d_in, const int* in_sizes, int n_in,
                              void* d_out, int out_size, void* d_ws, size_t ws_size,
                              hipStream_t stream) {
    const float* X     = (const float*)d_in[0];   // (B,S,H)
    const float* W_uv  = (const float*)d_in[1];   // (H, 4224)
    const float* b_uv  = (const float*)d_in[2];   // (4224,)
    const float* gamma = (const float*)d_in[3];   // (2,128)
    const float* beta  = (const float*)d_in[4];   // (2,128)
    const float* W_out = (const float*)d_in[5];   // (E, H)
    const float* b_out = (const float*)d_in[6];   // (H,)
    float* out = (float*)d_out;

    // workspace carve-up (fp32): u, v, q, k, sq  = 200 MiB total
    float* u  = (float*)d_ws;                         // M_TOT x E
    float* v  = u  + (long)M_TOT * E_DIM;             // M_TOT x E
    float* q  = v  + (long)M_TOT * E_DIM;             // M_TOT x SD
    float* kk = q  + (long)M_TOT * SD;                // M_TOT x SD
    float* sq = kk + (long)M_TOT * SD;                // B x S x S

    // MODE 0: uvb GEMM  (8192 x 4224, K=1024)
    gemm_k<0><<<dim3(F_DIM / 128, M_TOT / 128, 1), 256, 0, stream>>>(
        X, W_uv, u, v, q, kk, b_uv, gamma, beta);

    // MODE 1: sq = relu(q k^T / S)^2   (batched, 2048 x 2048, K=128)
    gemm_k<1><<<dim3(S_LEN / 128, S_LEN / 128, B_SZ), 256, 0, stream>>>(
        q, kk, sq, nullptr, nullptr, nullptr, nullptr, nullptr, nullptr);

    // MODE 2: u = u * (sq @ v)   (batched, 2048 x 2048, K=2048)
    gemm_k<2><<<dim3(E_DIM / 128, S_LEN / 128, B_SZ), 256, 0, stream>>>(
        sq, v, u, nullptr, nullptr, nullptr, nullptr, nullptr, nullptr);

    // MODE 3: out = u @ W_out + b_out   (8192 x 1024, K=2048)
    gemm_k<3><<<dim3(H_DIM / 128, M_TOT / 128, 1), 256, 0, stream>>>(
        u, W_out, out, nullptr, nullptr, nullptr, b_out, nullptr, nullptr);
}

// Round 2
// 487.966 us; speedup vs baseline: 4.5139x; 4.5139x over previous
//
#include <hip/hip_runtime.h>
#include <stdint.h>

// FLASH_6073083756839 — fp16-MFMA pipeline (R2).
//  prep:   cast X->fp16; transpose+cast W_uv -> Wuvt[f][h]; W_out -> Wt[h][e]
//  qk_gemm (fp32): q,k = gamma*silu(X@W_uv[:,4096:]+b)+beta   (precision-critical path)
//  mfma<0>: u(fp32), v_t(fp16, [b][e][s]) = silu(Xh @ Wuvt^T + b)   cols 0..4095
//  scores  (fp32): sq = fp16( (relu(q@k^T)*2^6)^2 )   == relu(scores/S)^2 * 2^34
//  mfma<2>: p = fp16( u * (sq @ v_t^T) )              (carries 2^34 scale)
//  mfma<3>: out = (p @ Wt^T) * 2^-34 + b_out          (fp32)

#define H_DIM  1024
#define E_DIM  2048
#define SD     128
#define B_SZ   4
#define S_LEN  2048
#define M_TOT  (B_SZ * S_LEN)          // 8192
#define F_DIM  (2 * E_DIM + SD)        // 4224

typedef _Float16 f16;
typedef __attribute__((ext_vector_type(4))) _Float16 f16x4;
typedef __attribute__((ext_vector_type(8))) _Float16 f16x8;
typedef __attribute__((ext_vector_type(4))) float f32x4;

__device__ __forceinline__ float silu_f(float x) { return x / (1.f + __expf(-x)); }

__device__ __forceinline__ void gload16(const void* g, void* l) {
  __builtin_amdgcn_global_load_lds(
      (const __attribute__((address_space(1))) void*)(uintptr_t)g,
      (__attribute__((address_space(3))) void*)(uint32_t)(uintptr_t)l,
      16, 0, 0);
}

// ---------------- prep kernels ----------------
__global__ __launch_bounds__(256) void cast_f16_k(const float* __restrict__ src,
                                                  f16* __restrict__ dst, long n) {
  long i = ((long)blockIdx.x * 256 + threadIdx.x) * 4;
  if (i < n) {
    float4 v = *(const float4*)(src + i);
    f16x4 h; h[0] = (f16)v.x; h[1] = (f16)v.y; h[2] = (f16)v.z; h[3] = (f16)v.w;
    *(f16x4*)(dst + i) = h;
  }
}

// dst[c][r] = (f16) src[r][c]; src is R x C
__global__ __launch_bounds__(256) void transpose_cast_k(const float* __restrict__ src,
                                                        f16* __restrict__ dst, int R, int C) {
  __shared__ float tile[32][33];
  int c0 = blockIdx.x * 32, r0 = blockIdx.y * 32;
  int tx = threadIdx.x & 31, ty = threadIdx.x >> 5;  // ty 0..7
  for (int i = ty; i < 32; i += 8) tile[i][tx] = src[(long)(r0 + i) * C + c0 + tx];
  __syncthreads();
  for (int i = ty; i < 32; i += 8) dst[(long)(c0 + i) * R + r0 + tx] = (f16)tile[tx][i];
}

// ---------------- fp32 q/k producer (base columns 4096..4223) ----------------
__global__ __launch_bounds__(256) void qk_gemm(
    const float* __restrict__ X, const float* __restrict__ Wuv,
    const float* __restrict__ b_uv, const float* __restrict__ gamma,
    const float* __restrict__ beta, float* __restrict__ q, float* __restrict__ kk)
{
  __shared__ float As[16][68];   // [k][m]
  __shared__ float Bs[16][68];   // [k][n]
  const int t  = threadIdx.x;
  const int m0 = blockIdx.y * 64;
  const int n0 = blockIdx.x * 64;
  const int arow = t >> 2, acol = (t & 3) * 4;
  const int brow = t >> 4, bcol = (t & 15) * 4;
  const int tm = (t >> 4) * 4, tn = (t & 15) * 4;
  float acc[4][4] = {};
  for (int k0 = 0; k0 < H_DIM; k0 += 16) {
    float4 a = *(const float4*)(X + (long)(m0 + arow) * H_DIM + k0 + acol);
    As[acol + 0][arow] = a.x; As[acol + 1][arow] = a.y;
    As[acol + 2][arow] = a.z; As[acol + 3][arow] = a.w;
    float4 b = *(const float4*)(Wuv + (long)(k0 + brow) * F_DIM + 2 * E_DIM + n0 + bcol);
    *(float4*)&Bs[brow][bcol] = b;
    __syncthreads();
#pragma unroll
    for (int kx = 0; kx < 16; kx++) {
      float a4[4], b4[4];
      *(float4*)a4 = *(const float4*)&As[kx][tm];
      *(float4*)b4 = *(const float4*)&Bs[kx][tn];
#pragma unroll
      for (int i = 0; i < 4; i++)
#pragma unroll
        for (int j = 0; j < 4; j++) acc[i][j] += a4[i] * b4[j];
    }
    __syncthreads();
  }
#pragma unroll
  for (int i = 0; i < 4; i++) {
    int gr = m0 + tm + i;
#pragma unroll
    for (int j = 0; j < 4; j++) {
      int gc = n0 + tn + j;                       // 0..127
      float s = silu_f(acc[i][j] + b_uv[2 * E_DIM + gc]);
      q[(long)gr * SD + gc]  = s * gamma[gc]      + beta[gc];
      kk[(long)gr * SD + gc] = s * gamma[SD + gc] + beta[SD + gc];
    }
  }
}

// ---------------- fp32 scores: sq = (relu(q@k^T)*64)^2 as fp16 ----------------
__global__ __launch_bounds__(256) void scores_gemm(
    const float* __restrict__ qg, const float* __restrict__ kg, f16* __restrict__ sq)
{
  const int z = blockIdx.z;
  const float* A  = qg + (long)z * S_LEN * SD;
  const float* Bp = kg + (long)z * S_LEN * SD;
  __shared__ float As[16][132];
  __shared__ float Bs[16][132];
  const int t  = threadIdx.x;
  const int m0 = blockIdx.y * 128;
  const int n0 = blockIdx.x * 128;
  const int arow = t >> 1;
  const int acol = (t & 1) * 8;
  const int tm = (t >> 4) * 8;
  const int tn = (t & 15) * 8;
  float acc[8][8] = {};
  for (int k0 = 0; k0 < SD; k0 += 16) {
    {
      const float* src = A + (long)(m0 + arow) * SD + k0 + acol;
      float4 a0 = *(const float4*)(src);
      float4 a1 = *(const float4*)(src + 4);
      As[acol + 0][arow] = a0.x; As[acol + 1][arow] = a0.y;
      As[acol + 2][arow] = a0.z; As[acol + 3][arow] = a0.w;
      As[acol + 4][arow] = a1.x; As[acol + 5][arow] = a1.y;
      As[acol + 6][arow] = a1.z; As[acol + 7][arow] = a1.w;
    }
    {
      const float* src = Bp + (long)(n0 + arow) * SD + k0 + acol;
      float4 b0 = *(const float4*)(src);
      float4 b1 = *(const float4*)(src + 4);
      Bs[acol + 0][arow] = b0.x; Bs[acol + 1][arow] = b0.y;
      Bs[acol + 2][arow] = b0.z; Bs[acol + 3][arow] = b0.w;
      Bs[acol + 4][arow] = b1.x; Bs[acol + 5][arow] = b1.y;
      Bs[acol + 6][arow] = b1.z; Bs[acol + 7][arow] = b1.w;
    }
    __syncthreads();
#pragma unroll
    for (int kx = 0; kx < 16; kx++) {
      float a[8], b[8];
      *(float4*)&a[0] = *(const float4*)&As[kx][tm];
      *(float4*)&a[4] = *(const float4*)&As[kx][tm + 4];
      *(float4*)&b[0] = *(const float4*)&Bs[kx][tn];
      *(float4*)&b[4] = *(const float4*)&Bs[kx][tn + 4];
#pragma unroll
      for (int i = 0; i < 8; i++)
#pragma unroll
        for (int j = 0; j < 8; j++) acc[i][j] += a[i] * b[j];
    }
    __syncthreads();
  }
#pragma unroll
  for (int i = 0; i < 8; i++) {
    int gr = m0 + tm + i;
#pragma unroll
    for (int j = 0; j < 8; j++) {
      int gc = n0 + tn + j;
      float tv = fmaxf(acc[i][j], 0.f) * 64.f;   // *2^6 -> squared carries 2^12 = (1/S^2)*2^34
      sq[(long)z * S_LEN * S_LEN + (long)gr * S_LEN + gc] = (f16)(tv * tv);
    }
  }
}

// ---------------- fp16 MFMA GEMM (modes 0, 2, 3) ----------------
// A: [m][k] fp16, row stride K.  B: [n][k] fp16 (pre-transposed), row stride K.
template <int MODE>
__global__ __launch_bounds__(256) void mfma_gemm(
    const f16* __restrict__ Ag, const f16* __restrict__ Bg,
    float* __restrict__ F0, f16* __restrict__ H0,
    const float* __restrict__ C0)
{
  constexpr int K   = (MODE == 0) ? H_DIM : 2048;
  constexpr int LDA = K, LDB = K;

  __shared__ f16 As[128][32];
  __shared__ f16 Bs[128][32];

  const int t    = threadIdx.x;
  const int w    = t >> 6;
  const int lane = t & 63;
  const int l16  = lane & 15;
  const int quad = lane >> 4;
  const int wy   = w >> 1, wx = w & 1;
  const int m0   = blockIdx.y * 128;
  const int n0   = blockIdx.x * 128;
  const long z   = blockIdx.z;

  const f16* A = Ag + (MODE == 2 ? z * (long)S_LEN * S_LEN : 0);
  const f16* B = Bg + (MODE == 2 ? z * (long)E_DIM * S_LEN : 0);

  const int srow = lane >> 2;        // 0..15
  const int scol = (lane & 3) * 8;   // f16 elems (16B chunks)

  f32x4 acc[4][4] = {};

  for (int k0 = 0; k0 < K; k0 += 32) {
    const f16* gA = A + (long)(m0 + (w << 5) + srow) * LDA + k0 + scol;
    const f16* gB = B + (long)(n0 + (w << 5) + srow) * LDB + k0 + scol;
    gload16(gA,                  &As[(w << 5)][0]);
    gload16(gA + (long)16 * LDA, &As[(w << 5) + 16][0]);
    gload16(gB,                  &Bs[(w << 5)][0]);
    gload16(gB + (long)16 * LDB, &Bs[(w << 5) + 16][0]);
    __syncthreads();

    f16x8 av[4], bv[4];
#pragma unroll
    for (int i = 0; i < 4; i++)
      av[i] = *(const f16x8*)&As[(wy << 6) + (i << 4) + l16][quad << 3];
#pragma unroll
    for (int j = 0; j < 4; j++)
      bv[j] = *(const f16x8*)&Bs[(wx << 6) + (j << 4) + l16][quad << 3];
#pragma unroll
    for (int i = 0; i < 4; i++)
#pragma unroll
      for (int j = 0; j < 4; j++)
        acc[i][j] = __builtin_amdgcn_mfma_f32_16x16x32_f16(av[i], bv[j], acc[i][j], 0, 0, 0);
    __syncthreads();
  }

  // C/D layout: col = lane&15, row = quad*4 + reg  [m89-verified]
  const int rbase = m0 + (wy << 6) + (quad << 2);
  const int cbase = n0 + (wx << 6) + l16;

  if (MODE == 0) {
    if (n0 < E_DIM) {                 // u region: fp32 row-major
#pragma unroll
      for (int i = 0; i < 4; i++)
#pragma unroll
        for (int j = 0; j < 4; j++) {
          int gc = cbase + (j << 4);
          float bias = C0[gc];
#pragma unroll
          for (int r = 0; r < 4; r++) {
            int gr = rbase + (i << 4) + r;
            F0[(long)gr * E_DIM + gc] = silu_f(acc[i][j][r] + bias);
          }
        }
    } else {                          // v region: fp16, transposed [b][e][s]
#pragma unroll
      for (int i = 0; i < 4; i++) {
        int gr0 = rbase + (i << 4);
        int b   = gr0 >> 11;          // /S_LEN
        int s0  = gr0 & (S_LEN - 1);
#pragma unroll
        for (int j = 0; j < 4; j++) {
          int gc = cbase + (j << 4);
          float bias = C0[gc];
          f16x4 pk;
#pragma unroll
          for (int r = 0; r < 4; r++) pk[r] = (f16)silu_f(acc[i][j][r] + bias);
          *(f16x4*)&H0[((long)b * E_DIM + (gc - E_DIM)) * S_LEN + s0] = pk;
        }
      }
    }
  } else if (MODE == 2) {             // p = fp16(u * attn_v_scaled)
    const long rowoff = z * S_LEN;
#pragma unroll
    for (int i = 0; i < 4; i++)
#pragma unroll
      for (int j = 0; j < 4; j++) {
        int gc = cbase + (j << 4);
#pragma unroll
        for (int r = 0; r < 4; r++) {
          int gr = rbase + (i << 4) + r;
          long idx = (rowoff + gr) * (long)E_DIM + gc;
          H0[idx] = (f16)(F0[idx] * acc[i][j][r]);
        }
      }
  } else {                            // MODE 3: out = acc*2^-34 + b_out
#pragma unroll
    for (int i = 0; i < 4; i++)
#pragma unroll
      for (int j = 0; j < 4; j++) {
        int gc = cbase + (j << 4);
        float bias = C0[gc];
#pragma unroll
        for (int r = 0; r < 4; r++) {
          int gr = rbase + (i << 4) + r;
          F0[(long)gr * H_DIM + gc] = acc[i][j][r] * (1.0f / 17179869184.0f) + bias;
        }
      }
  }
}

extern "C" void kernel_launch(void* const* d_in, const int* in_sizes, int n_in,
                              void* d_out, int out_size, void* d_ws, size_t ws_size,
                              hipStream_t stream) {
  const float* X     = (const float*)d_in[0];
  const float* W_uv  = (const float*)d_in[1];
  const float* b_uv  = (const float*)d_in[2];
  const float* gamma = (const float*)d_in[3];
  const float* beta  = (const float*)d_in[4];
  const float* W_out = (const float*)d_in[5];
  const float* b_out = (const float*)d_in[6];
  float* out = (float*)d_out;

  char* wp = (char*)d_ws;
  f16*   Xh   = (f16*)wp;   wp += (long)M_TOT * H_DIM * 2;   // 16 MB
  f16*   Wuvt = (f16*)wp;   wp += (long)F_DIM * H_DIM * 2;   // 8.65 MB
  f16*   Wt   = (f16*)wp;   wp += (long)H_DIM * E_DIM * 2;   // 4 MB
  float* u    = (float*)wp; wp += (long)M_TOT * E_DIM * 4;   // 64 MB
  f16*   vt   = (f16*)wp;   wp += (long)M_TOT * E_DIM * 2;   // 32 MB
  float* q    = (float*)wp; wp += (long)M_TOT * SD * 4;      // 4 MB
  float* kk   = (float*)wp; wp += (long)M_TOT * SD * 4;      // 4 MB
  f16*   sq   = (f16*)wp;   wp += (long)B_SZ * S_LEN * S_LEN * 2; // 32 MB
  f16*   p    = (f16*)wp;   wp += (long)M_TOT * E_DIM * 2;   // 32 MB

  // prep
  cast_f16_k<<<(M_TOT * H_DIM) / (256 * 4), 256, 0, stream>>>(X, Xh, (long)M_TOT * H_DIM);
  transpose_cast_k<<<dim3(F_DIM / 32, H_DIM / 32), 256, 0, stream>>>(W_uv, Wuvt, H_DIM, F_DIM);
  transpose_cast_k<<<dim3(H_DIM / 32, E_DIM / 32), 256, 0, stream>>>(W_out, Wt, E_DIM, H_DIM);

  // q,k (fp32 precision path)
  qk_gemm<<<dim3(2, M_TOT / 64), 256, 0, stream>>>(X, W_uv, b_uv, gamma, beta, q, kk);

  // u, v_t (fp16 MFMA over first 4096 columns)
  mfma_gemm<0><<<dim3(2 * E_DIM / 128, M_TOT / 128, 1), 256, 0, stream>>>(
      Xh, Wuvt, u, vt, b_uv);

  // sq (fp32, scaled fp16 out)
  scores_gemm<<<dim3(S_LEN / 128, S_LEN / 128, B_SZ), 256, 0, stream>>>(q, kk, sq);

  // p = u * (sq @ v)
  mfma_gemm<2><<<dim3(E_DIM / 128, S_LEN / 128, B_SZ), 256, 0, stream>>>(
      sq, vt, u, p, nullptr);

  // out = p @ W_out * 2^-34 + b_out
  mfma_gemm<3><<<dim3(H_DIM / 128, M_TOT / 128, 1), 256, 0, stream>>>(
      p, Wt, out, nullptr, b_out);
}

// Round 3
// 465.483 us; speedup vs baseline: 4.7319x; 1.0483x over previous
//
#include <hip/hip_runtime.h>
#include <stdint.h>

// FLASH_6073083756839 — all-fp16-MFMA pipeline (R3).
//  prep:    cast X->fp16; transpose+cast W_uv -> Wuvt[f][h]; W_out -> Wt[h][e]
//  mfma<0>: full uvb GEMM (N=4224). Epilogue: u(fp16), v_t(fp16 [b][e][s]),
//           q,k (fp16, = gamma*silu+beta) from the base columns.
//  mfma<1>: sq = fp16( (relu(q@k^T)*2^6)^2 )  == relu(scores/S)^2 * 2^34
//  mfma<2>: p = fp16( u * (sq @ v_t^T) )      (carries 2^34 scale)
//  mfma<3>: out = (p @ Wt^T) * 2^-34 + b_out  (fp32)

#define H_DIM  1024
#define E_DIM  2048
#define SD     128
#define B_SZ   4
#define S_LEN  2048
#define M_TOT  (B_SZ * S_LEN)          // 8192
#define F_DIM  (2 * E_DIM + SD)        // 4224

typedef _Float16 f16;
typedef __attribute__((ext_vector_type(4))) _Float16 f16x4;
typedef __attribute__((ext_vector_type(8))) _Float16 f16x8;
typedef __attribute__((ext_vector_type(4))) float f32x4;

__device__ __forceinline__ float silu_f(float x) { return x / (1.f + __expf(-x)); }

__device__ __forceinline__ void gload16(const void* g, void* l) {
  __builtin_amdgcn_global_load_lds(
      (const __attribute__((address_space(1))) void*)(uintptr_t)g,
      (__attribute__((address_space(3))) void*)(uint32_t)(uintptr_t)l,
      16, 0, 0);
}

// ---------------- prep kernels ----------------
__global__ __launch_bounds__(256) void cast_f16_k(const float* __restrict__ src,
                                                  f16* __restrict__ dst, long n) {
  long i = ((long)blockIdx.x * 256 + threadIdx.x) * 4;
  if (i < n) {
    float4 v = *(const float4*)(src + i);
    f16x4 h; h[0] = (f16)v.x; h[1] = (f16)v.y; h[2] = (f16)v.z; h[3] = (f16)v.w;
    *(f16x4*)(dst + i) = h;
  }
}

// dst[c][r] = (f16) src[r][c]; src is R x C
__global__ __launch_bounds__(256) void transpose_cast_k(const float* __restrict__ src,
                                                        f16* __restrict__ dst, int R, int C) {
  __shared__ float tile[32][33];
  int c0 = blockIdx.x * 32, r0 = blockIdx.y * 32;
  int tx = threadIdx.x & 31, ty = threadIdx.x >> 5;  // ty 0..7
  for (int i = ty; i < 32; i += 8) tile[i][tx] = src[(long)(r0 + i) * C + c0 + tx];
  __syncthreads();
  for (int i = ty; i < 32; i += 8) dst[(long)(c0 + i) * R + r0 + tx] = (f16)tile[tx][i];
}

// ---------------- fp16 MFMA GEMM (all 4 modes) ----------------
// A: [m][k] fp16, row stride = K.  B: [n][k] fp16 (pre-transposed), row stride = K.
//  MODE 0: K=1024, N=4224. epilogue u/v/q/k.     MODE 1: K=128,  scores->sq.
//  MODE 2: K=2048, p = u*(sq@v^T).               MODE 3: K=2048, out fp32.
template <int MODE>
__global__ __launch_bounds__(256) void mfma_gemm(
    const f16* __restrict__ Ag, const f16* __restrict__ Bg,
    float* __restrict__ F0, f16* __restrict__ H0, const f16* __restrict__ H1,
    f16* __restrict__ H2, f16* __restrict__ H3,
    const float* __restrict__ C0, const float* __restrict__ C1,
    const float* __restrict__ C2)
{
  constexpr int K   = (MODE == 0) ? H_DIM : (MODE == 1) ? SD : 2048;
  constexpr int LDA = K, LDB = K;

  __shared__ f16 As[128][32];
  __shared__ f16 Bs[128][32];

  const int t    = threadIdx.x;
  const int w    = t >> 6;
  const int lane = t & 63;
  const int l16  = lane & 15;
  const int quad = lane >> 4;
  const int wy   = w >> 1, wx = w & 1;
  const int m0   = blockIdx.y * 128;
  const int n0   = blockIdx.x * 128;
  const long z   = blockIdx.z;

  const f16* A = Ag + (MODE == 1 ? z * (long)S_LEN * SD
                     : MODE == 2 ? z * (long)S_LEN * S_LEN : 0);
  const f16* B = Bg + (MODE == 1 ? z * (long)S_LEN * SD
                     : MODE == 2 ? z * (long)E_DIM * S_LEN : 0);

  const int srow = lane >> 2;        // 0..15
  const int scol = (lane & 3) * 8;   // f16 elems (16B chunks)

  f32x4 acc[4][4] = {};

  for (int k0 = 0; k0 < K; k0 += 32) {
    const f16* gA = A + (long)(m0 + (w << 5) + srow) * LDA + k0 + scol;
    const f16* gB = B + (long)(n0 + (w << 5) + srow) * LDB + k0 + scol;
    gload16(gA,                  &As[(w << 5)][0]);
    gload16(gA + (long)16 * LDA, &As[(w << 5) + 16][0]);
    gload16(gB,                  &Bs[(w << 5)][0]);
    gload16(gB + (long)16 * LDB, &Bs[(w << 5) + 16][0]);
    __syncthreads();

    f16x8 av[4], bv[4];
#pragma unroll
    for (int i = 0; i < 4; i++)
      av[i] = *(const f16x8*)&As[(wy << 6) + (i << 4) + l16][quad << 3];
#pragma unroll
    for (int j = 0; j < 4; j++)
      bv[j] = *(const f16x8*)&Bs[(wx << 6) + (j << 4) + l16][quad << 3];
#pragma unroll
    for (int i = 0; i < 4; i++)
#pragma unroll
      for (int j = 0; j < 4; j++)
        acc[i][j] = __builtin_amdgcn_mfma_f32_16x16x32_f16(av[i], bv[j], acc[i][j], 0, 0, 0);
    __syncthreads();
  }

  // C/D layout: col = lane&15, row = quad*4 + reg  [m89-verified]
  const int rbase = m0 + (wy << 6) + (quad << 2);
  const int cbase = n0 + (wx << 6) + l16;

  if (MODE == 0) {
    if (n0 < E_DIM) {                 // u region: fp16 row-major [M][E]
#pragma unroll
      for (int i = 0; i < 4; i++)
#pragma unroll
        for (int j = 0; j < 4; j++) {
          int gc = cbase + (j << 4);
          float bias = C0[gc];
#pragma unroll
          for (int r = 0; r < 4; r++) {
            int gr = rbase + (i << 4) + r;
            H0[(long)gr * E_DIM + gc] = (f16)silu_f(acc[i][j][r] + bias);
          }
        }
    } else if (n0 < 2 * E_DIM) {      // v region: fp16, transposed [b][e][s]
#pragma unroll
      for (int i = 0; i < 4; i++) {
        int gr0 = rbase + (i << 4);
        int b   = gr0 >> 11;          // /S_LEN
        int s0  = gr0 & (S_LEN - 1);
#pragma unroll
        for (int j = 0; j < 4; j++) {
          int gc = cbase + (j << 4);
          float bias = C0[gc];
          f16x4 pk;
#pragma unroll
          for (int r = 0; r < 4; r++) pk[r] = (f16)silu_f(acc[i][j][r] + bias);
          *(f16x4*)&H1[((long)b * E_DIM + (gc - E_DIM)) * S_LEN + s0] = pk;
        }
      }
    } else {                          // base region -> q,k fp16 [M][SD]
#pragma unroll
      for (int i = 0; i < 4; i++)
#pragma unroll
        for (int j = 0; j < 4; j++) {
          int gc = cbase + (j << 4);
          int jj = gc - 2 * E_DIM;    // 0..127
          float bias = C0[gc];
          float g0 = C1[jj], g1 = C1[SD + jj];
          float be0 = C2[jj], be1 = C2[SD + jj];
#pragma unroll
          for (int r = 0; r < 4; r++) {
            int gr = rbase + (i << 4) + r;
            float s = silu_f(acc[i][j][r] + bias);
            H2[(long)gr * SD + jj] = (f16)(s * g0 + be0);   // q
            H3[(long)gr * SD + jj] = (f16)(s * g1 + be1);   // k
          }
        }
    }
  } else if (MODE == 1) {             // sq = (relu(q·k)*64)^2  (carries 2^34)
#pragma unroll
    for (int i = 0; i < 4; i++)
#pragma unroll
      for (int j = 0; j < 4; j++) {
        int gc = cbase + (j << 4);
#pragma unroll
        for (int r = 0; r < 4; r++) {
          int gr = rbase + (i << 4) + r;
          float tv = fmaxf(acc[i][j][r], 0.f) * 64.f;
          H0[z * (long)S_LEN * S_LEN + (long)gr * S_LEN + gc] = (f16)(tv * tv);
        }
      }
  } else if (MODE == 2) {             // p = fp16(u * attn_v_scaled)
    const long rowoff = z * S_LEN;
#pragma unroll
    for (int i = 0; i < 4; i++)
#pragma unroll
      for (int j = 0; j < 4; j++) {
        int gc = cbase + (j << 4);
#pragma unroll
        for (int r = 0; r < 4; r++) {
          int gr = rbase + (i << 4) + r;
          long idx = (rowoff + gr) * (long)E_DIM + gc;
          H0[idx] = (f16)((float)H1[idx] * acc[i][j][r]);
        }
      }
  } else {                            // MODE 3: out = acc*2^-34 + b_out (fp32)
#pragma unroll
    for (int i = 0; i < 4; i++)
#pragma unroll
      for (int j = 0; j < 4; j++) {
        int gc = cbase + (j << 4);
        float bias = C0[gc];
#pragma unroll
        for (int r = 0; r < 4; r++) {
          int gr = rbase + (i << 4) + r;
          F0[(long)gr * H_DIM + gc] = acc[i][j][r] * (1.0f / 17179869184.0f) + bias;
        }
      }
  }
}

extern "C" void kernel_launch(void* const* d_in, const int* in_sizes, int n_in,
                              void* d_out, int out_size, void* d_ws, size_t ws_size,
                              hipStream_t stream) {
  const float* X     = (const float*)d_in[0];
  const float* W_uv  = (const float*)d_in[1];
  const float* b_uv  = (const float*)d_in[2];
  const float* gamma = (const float*)d_in[3];
  const float* beta  = (const float*)d_in[4];
  const float* W_out = (const float*)d_in[5];
  const float* b_out = (const float*)d_in[6];
  float* out = (float*)d_out;

  char* wp = (char*)d_ws;
  f16* Xh   = (f16*)wp; wp += (long)M_TOT * H_DIM * 2;        // 16 MB
  f16* Wuvt = (f16*)wp; wp += (long)F_DIM * H_DIM * 2;        // 8.65 MB
  f16* Wt   = (f16*)wp; wp += (long)H_DIM * E_DIM * 2;        // 4 MB
  f16* u    = (f16*)wp; wp += (long)M_TOT * E_DIM * 2;        // 32 MB
  f16* vt   = (f16*)wp; wp += (long)M_TOT * E_DIM * 2;        // 32 MB
  f16* qh   = (f16*)wp; wp += (long)M_TOT * SD * 2;           // 2 MB
  f16* kh   = (f16*)wp; wp += (long)M_TOT * SD * 2;           // 2 MB
  f16* sq   = (f16*)wp; wp += (long)B_SZ * S_LEN * S_LEN * 2; // 32 MB
  f16* p    = (f16*)wp; wp += (long)M_TOT * E_DIM * 2;        // 32 MB

  // prep
  cast_f16_k<<<(M_TOT * H_DIM) / (256 * 4), 256, 0, stream>>>(X, Xh, (long)M_TOT * H_DIM);
  transpose_cast_k<<<dim3(F_DIM / 32, H_DIM / 32), 256, 0, stream>>>(W_uv, Wuvt, H_DIM, F_DIM);
  transpose_cast_k<<<dim3(H_DIM / 32, E_DIM / 32), 256, 0, stream>>>(W_out, Wt, E_DIM, H_DIM);

  // u, v_t, q, k  (full 4224-column GEMM)
  mfma_gemm<0><<<dim3(F_DIM / 128, M_TOT / 128, 1), 256, 0, stream>>>(
      Xh, Wuvt, nullptr, u, vt, qh, kh, b_uv, gamma, beta);

  // sq = (relu(q@k^T)*2^6)^2
  mfma_gemm<1><<<dim3(S_LEN / 128, S_LEN / 128, B_SZ), 256, 0, stream>>>(
      qh, kh, nullptr, sq, nullptr, nullptr, nullptr, nullptr, nullptr, nullptr);

  // p = u * (sq @ v)
  mfma_gemm<2><<<dim3(E_DIM / 128, S_LEN / 128, B_SZ), 256, 0, stream>>>(
      sq, vt, nullptr, p, u, nullptr, nullptr, nullptr, nullptr, nullptr);

  // out = p @ W_out * 2^-34 + b_out
  mfma_gemm<3><<<dim3(H_DIM / 128, M_TOT / 128, 1), 256, 0, stream>>>(
      p, Wt, out, nullptr, nullptr, nullptr, nullptr, b_out, nullptr, nullptr);
}

// Round 4
// 404.749 us; speedup vs baseline: 5.4420x; 1.1501x over previous
//
#include <hip/hip_runtime.h>
#include <stdint.h>

// FLASH_6073083756839 — all-fp16-MFMA pipeline (R4).
//  prep:    cast X->fp16; transpose+cast W_uv -> Wuvt[f][h]; W_out -> Wt[h][e]
//  mfma<0>: u/v GEMM (N=4096, slim epilogue): u(fp16 [M][E]), v_t(fp16 [b][e][s])
//  mfma<4>: q,k GEMM (base 128 cols): q,k = fp16(gamma*silu(acc+b)+beta)
//  mfma<1>: sq = fp16( (relu(q@k^T)*2^6)^2 )  == relu(scores/S)^2 * 2^34
//  mfma<2>: p = fp16( u * (sq @ v_t^T) )      (carries 2^34 scale)
//  mfma<3>: out = (p @ Wt^T) * 2^-34 + b_out  (fp32)

#define H_DIM  1024
#define E_DIM  2048
#define SD     128
#define B_SZ   4
#define S_LEN  2048
#define M_TOT  (B_SZ * S_LEN)          // 8192
#define F_DIM  (2 * E_DIM + SD)        // 4224

typedef _Float16 f16;
typedef __attribute__((ext_vector_type(4))) _Float16 f16x4;
typedef __attribute__((ext_vector_type(8))) _Float16 f16x8;
typedef __attribute__((ext_vector_type(4))) float f32x4;

__device__ __forceinline__ float silu_f(float x) { return x / (1.f + __expf(-x)); }

__device__ __forceinline__ void gload16(const void* g, void* l) {
  __builtin_amdgcn_global_load_lds(
      (const __attribute__((address_space(1))) void*)(uintptr_t)g,
      (__attribute__((address_space(3))) void*)(uint32_t)(uintptr_t)l,
      16, 0, 0);
}

// ---------------- prep kernels ----------------
__global__ __launch_bounds__(256) void cast_f16_k(const float* __restrict__ src,
                                                  f16* __restrict__ dst, long n) {
  long i = ((long)blockIdx.x * 256 + threadIdx.x) * 4;
  if (i < n) {
    float4 v = *(const float4*)(src + i);
    f16x4 h; h[0] = (f16)v.x; h[1] = (f16)v.y; h[2] = (f16)v.z; h[3] = (f16)v.w;
    *(f16x4*)(dst + i) = h;
  }
}

// dst[c][r] = (f16) src[r][c]; src is R x C
__global__ __launch_bounds__(256) void transpose_cast_k(const float* __restrict__ src,
                                                        f16* __restrict__ dst, int R, int C) {
  __shared__ float tile[32][33];
  int c0 = blockIdx.x * 32, r0 = blockIdx.y * 32;
  int tx = threadIdx.x & 31, ty = threadIdx.x >> 5;  // ty 0..7
  for (int i = ty; i < 32; i += 8) tile[i][tx] = src[(long)(r0 + i) * C + c0 + tx];
  __syncthreads();
  for (int i = ty; i < 32; i += 8) dst[(long)(c0 + i) * R + r0 + tx] = (f16)tile[tx][i];
}

// ---------------- fp16 MFMA GEMM ----------------
// A: [m][k] fp16, row stride = K.  B: [n][k] fp16 (pre-transposed), row stride = K.
//  MODE 0: K=1024, N=4096, u/v epilogue.   MODE 1: K=128,  scores->sq.
//  MODE 2: K=2048, p = u*(sq@v^T).         MODE 3: K=2048, out fp32.
//  MODE 4: K=1024, N=128, q/k epilogue.
template <int MODE>
__global__ __launch_bounds__(256) void mfma_gemm(
    const f16* __restrict__ Ag, const f16* __restrict__ Bg,
    float* __restrict__ F0, f16* __restrict__ H0, const f16* __restrict__ H1,
    f16* __restrict__ H2, f16* __restrict__ H3,
    const float* __restrict__ C0, const float* __restrict__ C1,
    const float* __restrict__ C2)
{
  constexpr int K   = (MODE == 1) ? SD : (MODE == 0 || MODE == 4) ? H_DIM : 2048;
  constexpr int LDA = K, LDB = K;

  __shared__ f16 As[128][32];
  __shared__ f16 Bs[128][32];

  const int t    = threadIdx.x;
  const int w    = t >> 6;
  const int lane = t & 63;
  const int l16  = lane & 15;
  const int quad = lane >> 4;
  const int wy   = w >> 1, wx = w & 1;
  const int m0   = blockIdx.y * 128;
  const int n0   = blockIdx.x * 128;
  const long z   = blockIdx.z;

  const f16* A = Ag + (MODE == 1 ? z * (long)S_LEN * SD
                     : MODE == 2 ? z * (long)S_LEN * S_LEN : 0);
  const f16* B = Bg + (MODE == 1 ? z * (long)S_LEN * SD
                     : MODE == 2 ? z * (long)E_DIM * S_LEN : 0);

  const int srow = lane >> 2;        // 0..15
  const int scol = (lane & 3) * 8;   // f16 elems (16B chunks)

  f32x4 acc[4][4] = {};

  for (int k0 = 0; k0 < K; k0 += 32) {
    const f16* gA = A + (long)(m0 + (w << 5) + srow) * LDA + k0 + scol;
    const f16* gB = B + (long)(n0 + (w << 5) + srow) * LDB + k0 + scol;
    gload16(gA,                  &As[(w << 5)][0]);
    gload16(gA + (long)16 * LDA, &As[(w << 5) + 16][0]);
    gload16(gB,                  &Bs[(w << 5)][0]);
    gload16(gB + (long)16 * LDB, &Bs[(w << 5) + 16][0]);
    __syncthreads();

    f16x8 av[4], bv[4];
#pragma unroll
    for (int i = 0; i < 4; i++)
      av[i] = *(const f16x8*)&As[(wy << 6) + (i << 4) + l16][quad << 3];
#pragma unroll
    for (int j = 0; j < 4; j++)
      bv[j] = *(const f16x8*)&Bs[(wx << 6) + (j << 4) + l16][quad << 3];
#pragma unroll
    for (int i = 0; i < 4; i++)
#pragma unroll
      for (int j = 0; j < 4; j++)
        acc[i][j] = __builtin_amdgcn_mfma_f32_16x16x32_f16(av[i], bv[j], acc[i][j], 0, 0, 0);
    __syncthreads();
  }

  // C/D layout: col = lane&15, row = quad*4 + reg  [m89-verified]
  const int rbase = m0 + (wy << 6) + (quad << 2);
  const int cbase = n0 + (wx << 6) + l16;

  if (MODE == 0) {
    if (n0 < E_DIM) {                 // u region: fp16 row-major [M][E]
#pragma unroll
      for (int i = 0; i < 4; i++)
#pragma unroll
        for (int j = 0; j < 4; j++) {
          int gc = cbase + (j << 4);
          float bias = C0[gc];
#pragma unroll
          for (int r = 0; r < 4; r++) {
            int gr = rbase + (i << 4) + r;
            H0[(long)gr * E_DIM + gc] = (f16)silu_f(acc[i][j][r] + bias);
          }
        }
    } else {                          // v region: fp16, transposed [b][e][s]
#pragma unroll
      for (int i = 0; i < 4; i++) {
        int gr0 = rbase + (i << 4);
        int b   = gr0 >> 11;          // /S_LEN
        int s0  = gr0 & (S_LEN - 1);
#pragma unroll
        for (int j = 0; j < 4; j++) {
          int gc = cbase + (j << 4);
          float bias = C0[gc];
          f16x4 pk;
#pragma unroll
          for (int r = 0; r < 4; r++) pk[r] = (f16)silu_f(acc[i][j][r] + bias);
          *(f16x4*)&H1[((long)b * E_DIM + (gc - E_DIM)) * S_LEN + s0] = pk;
        }
      }
    }
  } else if (MODE == 4) {             // q,k from base cols (n0 == 0, N=128)
#pragma unroll
    for (int i = 0; i < 4; i++)
#pragma unroll
      for (int j = 0; j < 4; j++) {
        int jj = cbase + (j << 4);    // 0..127
        float bias = C0[jj];
        float g0 = C1[jj], g1 = C1[SD + jj];
        float be0 = C2[jj], be1 = C2[SD + jj];
#pragma unroll
        for (int r = 0; r < 4; r++) {
          int gr = rbase + (i << 4) + r;
          float s = silu_f(acc[i][j][r] + bias);
          H2[(long)gr * SD + jj] = (f16)(s * g0 + be0);   // q
          H3[(long)gr * SD + jj] = (f16)(s * g1 + be1);   // k
        }
      }
  } else if (MODE == 1) {             // sq = (relu(q·k)*64)^2  (carries 2^34)
#pragma unroll
    for (int i = 0; i < 4; i++)
#pragma unroll
      for (int j = 0; j < 4; j++) {
        int gc = cbase + (j << 4);
#pragma unroll
        for (int r = 0; r < 4; r++) {
          int gr = rbase + (i << 4) + r;
          float tv = fmaxf(acc[i][j][r], 0.f) * 64.f;
          H0[z * (long)S_LEN * S_LEN + (long)gr * S_LEN + gc] = (f16)(tv * tv);
        }
      }
  } else if (MODE == 2) {             // p = fp16(u * attn_v_scaled)
    const long rowoff = z * S_LEN;
#pragma unroll
    for (int i = 0; i < 4; i++)
#pragma unroll
      for (int j = 0; j < 4; j++) {
        int gc = cbase + (j << 4);
#pragma unroll
        for (int r = 0; r < 4; r++) {
          int gr = rbase + (i << 4) + r;
          long idx = (rowoff + gr) * (long)E_DIM + gc;
          H0[idx] = (f16)((float)H1[idx] * acc[i][j][r]);
        }
      }
  } else {                            // MODE 3: out = acc*2^-34 + b_out (fp32)
#pragma unroll
    for (int i = 0; i < 4; i++)
#pragma unroll
      for (int j = 0; j < 4; j++) {
        int gc = cbase + (j << 4);
        float bias = C0[gc];
#pragma unroll
        for (int r = 0; r < 4; r++) {
          int gr = rbase + (i << 4) + r;
          F0[(long)gr * H_DIM + gc] = acc[i][j][r] * (1.0f / 17179869184.0f) + bias;
        }
      }
  }
}

extern "C" void kernel_launch(void* const* d_in, const int* in_sizes, int n_in,
                              void* d_out, int out_size, void* d_ws, size_t ws_size,
                              hipStream_t stream) {
  const float* X     = (const float*)d_in[0];
  const float* W_uv  = (const float*)d_in[1];
  const float* b_uv  = (const float*)d_in[2];
  const float* gamma = (const float*)d_in[3];
  const float* beta  = (const float*)d_in[4];
  const float* W_out = (const float*)d_in[5];
  const float* b_out = (const float*)d_in[6];
  float* out = (float*)d_out;

  char* wp = (char*)d_ws;
  f16* Xh   = (f16*)wp; wp += (long)M_TOT * H_DIM * 2;        // 16 MB
  f16* Wuvt = (f16*)wp; wp += (long)F_DIM * H_DIM * 2;        // 8.65 MB
  f16* Wt   = (f16*)wp; wp += (long)H_DIM * E_DIM * 2;        // 4 MB
  f16* u    = (f16*)wp; wp += (long)M_TOT * E_DIM * 2;        // 32 MB
  f16* vt   = (f16*)wp; wp += (long)M_TOT * E_DIM * 2;        // 32 MB
  f16* qh   = (f16*)wp; wp += (long)M_TOT * SD * 2;           // 2 MB
  f16* kh   = (f16*)wp; wp += (long)M_TOT * SD * 2;           // 2 MB
  f16* sq   = (f16*)wp; wp += (long)B_SZ * S_LEN * S_LEN * 2; // 32 MB
  f16* p    = (f16*)wp; wp += (long)M_TOT * E_DIM * 2;        // 32 MB

  // prep
  cast_f16_k<<<(M_TOT * H_DIM) / (256 * 4), 256, 0, stream>>>(X, Xh, (long)M_TOT * H_DIM);
  transpose_cast_k<<<dim3(F_DIM / 32, H_DIM / 32), 256, 0, stream>>>(W_uv, Wuvt, H_DIM, F_DIM);
  transpose_cast_k<<<dim3(H_DIM / 32, E_DIM / 32), 256, 0, stream>>>(W_out, Wt, E_DIM, H_DIM);

  // u, v_t  (N=4096, slim epilogue)
  mfma_gemm<0><<<dim3(2 * E_DIM / 128, M_TOT / 128, 1), 256, 0, stream>>>(
      Xh, Wuvt, nullptr, u, vt, nullptr, nullptr, b_uv, nullptr, nullptr);

  // q, k  (base 128 cols of W_uv)
  mfma_gemm<4><<<dim3(1, M_TOT / 128, 1), 256, 0, stream>>>(
      Xh, Wuvt + (long)2 * E_DIM * H_DIM, nullptr, nullptr, nullptr, qh, kh,
      b_uv + 2 * E_DIM, gamma, beta);

  // sq = (relu(q@k^T)*2^6)^2
  mfma_gemm<1><<<dim3(S_LEN / 128, S_LEN / 128, B_SZ), 256, 0, stream>>>(
      qh, kh, nullptr, sq, nullptr, nullptr, nullptr, nullptr, nullptr, nullptr);

  // p = u * (sq @ v)
  mfma_gemm<2><<<dim3(E_DIM / 128, S_LEN / 128, B_SZ), 256, 0, stream>>>(
      sq, vt, nullptr, p, u, nullptr, nullptr, nullptr, nullptr, nullptr);

  // out = p @ W_out * 2^-34 + b_out
  mfma_gemm<3><<<dim3(H_DIM / 128, M_TOT / 128, 1), 256, 0, stream>>>(
      p, Wt, out, nullptr, nullptr, nullptr, nullptr, b_out, nullptr, nullptr);
}